// Round 5
// baseline (1527.009 us; speedup 1.0000x reference)
//
#include <hip/hip_runtime.h>

// B=32, IN=16, C=8192, U=32, K=16, 3 routing iterations.
#define CC   8192
#define UU   32
#define BB   32
#define INU  16
#define UK   512
#define CPB    16     // channels per block
#define NCHUNK 512    // CC/CPB
#define XSTR  532     // x staging row stride (floats); 532%32=20 -> benign conflicts
#define MSTR  17      // msq row stride (pad to break 4-way bank aliasing)

template <int CTRL>
__device__ __forceinline__ float dpp_add(float x) {
  int p = __builtin_amdgcn_update_dpp(0, __float_as_int(x), CTRL, 0xF, 0xF, true);
  return x + __int_as_float(p);
}

// Sum across all 64 lanes (result in every lane): 16-lane rows via DPP, then xor16/32.
__device__ __forceinline__ float red64(float a) {
  a = dpp_add<0xB1>(a);    // ^1
  a = dpp_add<0x4E>(a);    // ^2
  a = dpp_add<0x141>(a);   // ^7 (row_half_mirror)
  a = dpp_add<0x140>(a);   // ^15 (row_mirror)
  a += __shfl_xor(a, 16);
  a += __shfl_xor(a, 32);
  return a;
}

// One routing pass, with the previous pass's squash folded into the prologue.
// Lane map: k=l&15, bg=l>>4 (8 b's per thread); wave w owns u0=4w (4 u's/thread).
// Block handles CPB=16 channels; b-logits live in lanes 0..15 of breg[j] per wave.
// grid=512 -> 2 blocks/CU resident at VGPR=128 (AGPR spill ok, no scratch).
__global__ __launch_bounds__(512, 4) void fused_pass(
    const float* __restrict__ x, const float* __restrict__ W,
    float* __restrict__ b_io,
    const float* __restrict__ S_prev, const float* __restrict__ Z_prev,
    float* __restrict__ S, float* __restrict__ Z, const int pass)
{
  __shared__ float xs[CPB * XSTR];     // ~34 KB
  __shared__ float zr_sh[UU];
  __shared__ float msq_sh[BB * MSTR];  // ~2.2 KB

  const int t  = threadIdx.x;
  const int l  = t & 63;
  const int k  = l & 15;
  const int bg = l >> 4;
  const int u0 = (t >> 6) * 4;
  const int dir = pass & 1;            // serpentine chunk order for L3 reuse of W
  const int chunk = dir ? (NCHUNK - 1 - blockIdx.x) : blockIdx.x;
  const int c0 = chunk * CPB;

  // ---- Prologue: v from previous pass's S/Z (squash), b-logits from global ----
  float v[4][8];
  float breg[4] = {0.f, 0.f, 0.f, 0.f};   // lane cc (0..15) holds b[c0+cc][u0+j]

  if (pass == 0) {
#pragma unroll
    for (int j = 0; j < 4; ++j)
#pragma unroll
      for (int bb = 0; bb < 8; ++bb) v[j][bb] = 0.f;   // uniform softmax exactly
  } else {
#pragma unroll
    for (int j = 0; j < 4; ++j)
      breg[j] = b_io[(size_t)(c0 + (l & 15)) * UU + u0 + j];

    if (t < UU) zr_sh[t] = 1.0f / Z_prev[t];
    __syncthreads();
    {
      const int b = t >> 4, k2 = t & 15;
      float m = 0.f;
#pragma unroll
      for (int uu = 0; uu < UU; ++uu) {
        float s = S_prev[b * UK + uu * 16 + k2] * zr_sh[uu];
        m = fmaf(s, s, m);
      }
      msq_sh[b * MSTR + k2] = m;
    }
    __syncthreads();
    {
      float zr0 = zr_sh[u0], zr1 = zr_sh[u0 + 1], zr2 = zr_sh[u0 + 2], zr3 = zr_sh[u0 + 3];
#pragma unroll
      for (int bb = 0; bb < 8; ++bb) {
        const int b = bg * 8 + bb;
        float m = msq_sh[b * MSTR + k];
        float g = sqrtf(m) / (1.0f + m);        // v = s * mag/(1+mag_sq)
        v[0][bb] = S_prev[b * UK + (u0 + 0) * 16 + k] * zr0 * g;
        v[1][bb] = S_prev[b * UK + (u0 + 1) * 16 + k] * zr1 * g;
        v[2][bb] = S_prev[b * UK + (u0 + 2) * 16 + k] * zr2 * g;
        v[3][bb] = S_prev[b * UK + (u0 + 3) * 16 + k] * zr3 * g;
      }
    }
    __syncthreads();
  }

  // ---- Stage x for this block's 16 channels ----
#pragma unroll
  for (int jj = 0; jj < 16; ++jj) {
    int idx = jj * 512 + t;
    int ccl = idx & 15, bi = idx >> 4;      // bi = b*16 + i
    int b = bi >> 4, i = bi & 15;
    xs[ccl * XSTR + (b & 7) * 64 + (b >> 3) * 16 + i] = x[bi * CC + c0 + ccl];
  }
  __syncthreads();

  float Sl[4][8];
#pragma unroll
  for (int j = 0; j < 4; ++j)
#pragma unroll
    for (int bb = 0; bb < 8; ++bb) Sl[j][bb] = 0.f;
  float zloc[4] = {0.f, 0.f, 0.f, 0.f};

#pragma unroll 1
  for (int cc = 0; cc < CPB; ++cc) {
    const int c = c0 + cc;

    // W rows (u0..u0+3) at this k: 16 dwordx4, fully coalesced per wave.
    float4 wq[4][4];
    {
      const float4* wp = (const float4*)(W + ((size_t)c * UK + u0 * 16 + k) * INU);
#pragma unroll
      for (int j = 0; j < 4; ++j)
#pragma unroll
        for (int q = 0; q < 4; ++q) wq[j][q] = wp[j * 64 + q];
    }

    float uh[4][8];
    float ap[4] = {0.f, 0.f, 0.f, 0.f};
    const float* xr0 = xs + cc * XSTR + bg * 16;
#pragma unroll
    for (int bb = 0; bb < 8; ++bb) {
      const float4* xr = (const float4*)(xr0 + bb * 64);
      float4 x0 = xr[0], x1 = xr[1], x2 = xr[2], x3 = xr[3];
#pragma unroll
      for (int j = 0; j < 4; ++j) {
        float h;
        h = wq[j][0].x * x0.x;
        h = fmaf(wq[j][0].y, x0.y, h); h = fmaf(wq[j][0].z, x0.z, h); h = fmaf(wq[j][0].w, x0.w, h);
        h = fmaf(wq[j][1].x, x1.x, h); h = fmaf(wq[j][1].y, x1.y, h);
        h = fmaf(wq[j][1].z, x1.z, h); h = fmaf(wq[j][1].w, x1.w, h);
        h = fmaf(wq[j][2].x, x2.x, h); h = fmaf(wq[j][2].y, x2.y, h);
        h = fmaf(wq[j][2].z, x2.z, h); h = fmaf(wq[j][2].w, x2.w, h);
        h = fmaf(wq[j][3].x, x3.x, h); h = fmaf(wq[j][3].y, x3.y, h);
        h = fmaf(wq[j][3].z, x3.z, h); h = fmaf(wq[j][3].w, x3.w, h);
        uh[j][bb] = h;
        ap[j] = fmaf(h, v[j][bb], ap[j]);
      }
    }

#pragma unroll
    for (int j = 0; j < 4; ++j) ap[j] = red64(ap[j]);

#pragma unroll
    for (int j = 0; j < 4; ++j) {
      float bo = __int_as_float(__builtin_amdgcn_readlane(__float_as_int(breg[j]), cc));
      float bn = fmaf(ap[j], 0.03125f, bo);
      breg[j] = (l == cc) ? bn : breg[j];   // bn wave-uniform; lane cc keeps it
      float e = __expf(bn);
      zloc[j] += e;
#pragma unroll
      for (int bb = 0; bb < 8; ++bb) Sl[j][bb] = fmaf(e, uh[j][bb], Sl[j][bb]);
    }
  }

  // ---- Epilogue: flush partials, persist b ----
#pragma unroll
  for (int j = 0; j < 4; ++j)
#pragma unroll
    for (int bb = 0; bb < 8; ++bb)
      atomicAdd(S + (bg * 8 + bb) * UK + (u0 + j) * 16 + k, Sl[j][bb]);
  if (l == 0) {
#pragma unroll
    for (int j = 0; j < 4; ++j) atomicAdd(Z + u0 + j, zloc[j]);
  }
  if (pass < 2 && l < 16) {
#pragma unroll
    for (int j = 0; j < 4; ++j)
      b_io[(size_t)(c0 + l) * UU + u0 + j] = breg[j];
  }
}

// Final squash: s = S/Z ; mag_sq[b,k] = sum_u s^2 ; v = s*mag/(1+mag_sq).
__global__ void squash_k(const float* __restrict__ S, const float* __restrict__ Z,
                         float* __restrict__ vout)
{
  __shared__ float z_sh[UU];
  __shared__ float s2_sh[UK];
  __shared__ float mag_sh[16];

  const int b = blockIdx.x;   // 32
  const int t = threadIdx.x;  // 512 = uk

  if (t < UU) z_sh[t] = Z[t];
  float ssum = S[b * UK + t];
  __syncthreads();

  float s = ssum / z_sh[t >> 4];
  s2_sh[t] = s * s;
  __syncthreads();

  if (t < 16) {
    float m = 0.f;
    for (int uu = 0; uu < UU; ++uu) m += s2_sh[uu * 16 + t];
    mag_sh[t] = m;
  }
  __syncthreads();

  float msq = mag_sh[t & 15];
  vout[b * UK + t] = (msq / (1.0f + msq)) * s / sqrtf(msq);
}

extern "C" void kernel_launch(void* const* d_in, const int* in_sizes, int n_in,
                              void* d_out, int out_size, void* d_ws, size_t ws_size,
                              hipStream_t stream)
{
  const float* x = (const float*)d_in[0];   // (B, IN, C)
  const float* W = (const float*)d_in[1];   // (C, U, K, IN)
  float* out = (float*)d_out;               // (B, U, K, 1)

  char* ws = (char*)d_ws;
  const size_t SSLOT = (size_t)BB * UK * 4;           // 64 KB
  float* Sg  = (float*)ws;                            // 3 S slots
  float* Zg  = (float*)(ws + 3 * SSLOT);              // 3 Z slots (32 floats each)
  float* bio = (float*)(ws + 3 * SSLOT + 512);        // C*U floats (pass0 writes, no init)

  (void)hipMemsetAsync(ws, 0, 3 * SSLOT + 512, stream);

  for (int pass = 0; pass < 3; ++pass) {
    float* S  = Sg + pass * (BB * UK);
    float* Z  = Zg + pass * UU;
    const float* Sp = (pass > 0) ? (Sg + (pass - 1) * (BB * UK)) : Sg;
    const float* Zp = (pass > 0) ? (Zg + (pass - 1) * UU) : Zg;
    fused_pass<<<NCHUNK, 512, 0, stream>>>(x, W, bio, Sp, Zp, S, Z, pass);
  }
  squash_k<<<BB, 512, 0, stream>>>(Sg + 2 * (BB * UK), Zg + 2 * UU, out);
}

// Round 6
// 1027.739 us; speedup vs baseline: 1.4858x; 1.4858x over previous
//
#include <hip/hip_runtime.h>

// B=32, IN=16, C=8192, U=32, K=16, 3 routing iterations.
#define CC   8192
#define UU   32
#define BB   32
#define INU  16
#define UK   512
#define CPB  16        // channels per block
#define NCHUNK 512     // CC/CPB
#define XB   20        // xs per-b stride (floats): b*20%32 spans 8 bank-groups -> <=2-way
#define XC   644       // xs per-channel stride = 32*XB + 4 (644%32=4 -> staging writes 2-way)
#define MSTR 17

typedef __attribute__((ext_vector_type(8))) short bf16x8;
typedef __attribute__((ext_vector_type(4))) float f32x4;

__device__ __forceinline__ short bf1(float f) {
  unsigned u = __float_as_uint(f);
  u += 0x7fffu + ((u >> 16) & 1);          // RNE truncate to bf16
  return (short)(u >> 16);
}
__device__ __forceinline__ bf16x8 cvt8(float4 a, float4 b) {
  bf16x8 r;
  r[0]=bf1(a.x); r[1]=bf1(a.y); r[2]=bf1(a.z); r[3]=bf1(a.w);
  r[4]=bf1(b.x); r[5]=bf1(b.y); r[6]=bf1(b.z); r[7]=bf1(b.w);
  return r;
}

template <int CTRL>
__device__ __forceinline__ float dpp_add(float x) {
  int p = __builtin_amdgcn_update_dpp(0, __float_as_int(x), CTRL, 0xF, 0xF, true);
  return x + __int_as_float(p);
}
__device__ __forceinline__ float red64(float a) {
  a = dpp_add<0xB1>(a);    // ^1
  a = dpp_add<0x4E>(a);    // ^2
  a = dpp_add<0x141>(a);   // ^7
  a = dpp_add<0x140>(a);   // ^15
  a += __shfl_xor(a, 16);
  a += __shfl_xor(a, 32);
  return a;
}

// Stage x for 16 channels: xs[ccl][b][i], fp32.
__device__ __forceinline__ void stage_x(const float* __restrict__ x, float* xs,
                                        int c0, int t) {
#pragma unroll
  for (int jj = 0; jj < 16; ++jj) {
    int idx = jj * 512 + t;
    int ccl = idx & 15, bi = idx >> 4;     // bi = b*16 + i
    int b = bi >> 4, i = bi & 15;
    xs[ccl * XC + b * XB + i] = x[bi * CC + c0 + ccl];
  }
}

// MFMA fragment layouts (16x16x32 bf16, m89/m101-verified conventions):
//   A[m=lane&15][k=quad*8+j]   (quad=lane>>4; quads 2,3 hold k=16..31 -> zeros here)
//   B[k=quad*8+j][n=lane&15]
//   D[row=quad*4+r][col=lane&15]
// Mapping: m-tile == unit u (row=uk_local), n-tile nt: b = nt*16 + (lane&15).

// ---- Pass 0: v=0 => e=1 uniformly => S0 = sum_c u_hat. Pure GEMM + W->bf16 cache. ----
template <bool WBF>
__global__ __launch_bounds__(512, 2) void gemm0(
    const float* __restrict__ x, const float* __restrict__ W,
    float* __restrict__ S0, short* __restrict__ Wbf)
{
  __shared__ float xs[CPB * XC];
  const int t = threadIdx.x;
  const int l = t & 63;
  const int ln = l & 15, lq = l >> 4;
  const int u0 = (t >> 6) * 4;
  const int c0 = (int)blockIdx.x * CPB;

  stage_x(x, xs, c0, t);
  __syncthreads();

  const bf16x8 zfr = {0,0,0,0,0,0,0,0};
  f32x4 Sl[4][2];
#pragma unroll
  for (int j = 0; j < 4; ++j)
#pragma unroll
    for (int nt = 0; nt < 2; ++nt) Sl[j][nt] = (f32x4){0.f,0.f,0.f,0.f};

#pragma unroll 1
  for (int cc = 0; cc < CPB; ++cc) {
    const int c = c0 + cc;
    bf16x8 bfr0 = zfr, bfr1 = zfr;
    const float* xr = xs + cc * XC;
    if (l < 32) {
      const float4* p0 = (const float4*)(xr + ln * XB + lq * 8);
      bfr0 = cvt8(p0[0], p0[1]);
      const float4* p1 = (const float4*)(xr + (16 + ln) * XB + lq * 8);
      bfr1 = cvt8(p1[0], p1[1]);
    }
#pragma unroll
    for (int j = 0; j < 4; ++j) {
      const int u = u0 + j;
      bf16x8 af = zfr;
      if (l < 32) {
        const float4* wp = (const float4*)(W + ((size_t)c * UK + u * 16 + ln) * INU + lq * 8);
        af = cvt8(wp[0], wp[1]);
        if (WBF) *(bf16x8*)(Wbf + (((size_t)c * 32 + u) * 32 + l) * 8) = af;
      }
      Sl[j][0] = __builtin_amdgcn_mfma_f32_16x16x32_bf16(af, bfr0, Sl[j][0], 0, 0, 0);
      Sl[j][1] = __builtin_amdgcn_mfma_f32_16x16x32_bf16(af, bfr1, Sl[j][1], 0, 0, 0);
    }
  }

#pragma unroll
  for (int j = 0; j < 4; ++j)
#pragma unroll
    for (int nt = 0; nt < 2; ++nt)
#pragma unroll
      for (int r = 0; r < 4; ++r)
        atomicAdd(S0 + (nt * 16 + ln) * UK + (u0 + j) * 16 + lq * 4 + r, Sl[j][nt][r]);
}

// ---- Routing pass (PASS=1 or 2), squash of previous pass folded into prologue. ----
template <int PASS, bool WBF>
__global__ __launch_bounds__(512, 2) void route(
    const float* __restrict__ x, const float* __restrict__ W,
    const short* __restrict__ Wbf, float* __restrict__ b_io,
    const float* __restrict__ S_prev, const float* __restrict__ Z_prev,
    float* __restrict__ S, float* __restrict__ Z)
{
  __shared__ float xs[CPB * XC];
  __shared__ float zr_sh[UU];
  __shared__ float msq_sh[BB * MSTR];

  const int t = threadIdx.x;
  const int l = t & 63;
  const int ln = l & 15, lq = l >> 4;
  const int u0 = (t >> 6) * 4;
  const int chunk = (PASS & 1) ? (NCHUNK - 1 - (int)blockIdx.x) : (int)blockIdx.x;
  const int c0 = chunk * CPB;

  // Prologue: v = squash(S_prev/Z_prev) in D-fragment layout.
  if (t < UU) zr_sh[t] = (PASS == 1) ? (1.0f / 8192.0f) : (1.0f / Z_prev[t]);
  __syncthreads();
  {
    const int b = t >> 4, k2 = t & 15;
    float m = 0.f;
#pragma unroll
    for (int uu = 0; uu < UU; ++uu) {
      float s = S_prev[b * UK + uu * 16 + k2] * zr_sh[uu];
      m = fmaf(s, s, m);
    }
    msq_sh[b * MSTR + k2] = m;
  }
  __syncthreads();

  f32x4 v[4][2];
#pragma unroll
  for (int j = 0; j < 4; ++j) {
    const float zr = zr_sh[u0 + j];
#pragma unroll
    for (int nt = 0; nt < 2; ++nt) {
      const int b = nt * 16 + ln;
      float4 sv = *(const float4*)(S_prev + b * UK + (u0 + j) * 16 + lq * 4);
      f32x4 vv;
#pragma unroll
      for (int r = 0; r < 4; ++r) {
        float m = msq_sh[b * MSTR + lq * 4 + r];
        float g = sqrtf(m) / (1.0f + m);           // v = s * mag/(1+mag_sq)
        float sc = (r == 0 ? sv.x : r == 1 ? sv.y : r == 2 ? sv.z : sv.w);
        vv[r] = sc * zr * g;
      }
      v[j][nt] = vv;
    }
  }

  float breg[4];
  if (PASS == 2) {
#pragma unroll
    for (int j = 0; j < 4; ++j) breg[j] = b_io[(size_t)(c0 + ln) * UU + u0 + j];
  } else {
#pragma unroll
    for (int j = 0; j < 4; ++j) breg[j] = 0.f;
  }

  stage_x(x, xs, c0, t);
  __syncthreads();

  const bf16x8 zfr = {0,0,0,0,0,0,0,0};
  const f32x4 zero4 = {0.f,0.f,0.f,0.f};
  f32x4 Sl[4][2];
#pragma unroll
  for (int j = 0; j < 4; ++j)
#pragma unroll
    for (int nt = 0; nt < 2; ++nt) Sl[j][nt] = zero4;
  float zloc[4] = {0.f,0.f,0.f,0.f};

#pragma unroll 1
  for (int cc = 0; cc < CPB; ++cc) {
    const int c = c0 + cc;
    bf16x8 bfr0 = zfr, bfr1 = zfr;
    const float* xr = xs + cc * XC;
    if (l < 32) {
      const float4* p0 = (const float4*)(xr + ln * XB + lq * 8);
      bfr0 = cvt8(p0[0], p0[1]);
      const float4* p1 = (const float4*)(xr + (16 + ln) * XB + lq * 8);
      bfr1 = cvt8(p1[0], p1[1]);
    }
#pragma unroll
    for (int j = 0; j < 4; ++j) {
      const int u = u0 + j;
      bf16x8 af = zfr;
      if (l < 32) {
        if (WBF) {
          af = *(const bf16x8*)(Wbf + (((size_t)c * 32 + u) * 32 + l) * 8);
        } else {
          const float4* wp = (const float4*)(W + ((size_t)c * UK + u * 16 + ln) * INU + lq * 8);
          af = cvt8(wp[0], wp[1]);
        }
      }
      f32x4 uh0 = __builtin_amdgcn_mfma_f32_16x16x32_bf16(af, bfr0, zero4, 0, 0, 0);
      f32x4 uh1 = __builtin_amdgcn_mfma_f32_16x16x32_bf16(af, bfr1, zero4, 0, 0, 0);

      float ap = 0.f;
#pragma unroll
      for (int r = 0; r < 4; ++r) {
        ap = fmaf(uh0[r], v[j][0][r], ap);
        ap = fmaf(uh1[r], v[j][1][r], ap);
      }
      ap = red64(ap);

      float bo = __int_as_float(__builtin_amdgcn_readlane(__float_as_int(breg[j]), cc));
      float bn = fmaf(ap, 0.03125f, bo);
      if (PASS == 1) breg[j] = (l == cc) ? bn : breg[j];
      float e = __expf(bn);
      zloc[j] += e;
#pragma unroll
      for (int r = 0; r < 4; ++r) {
        Sl[j][0][r] = fmaf(e, uh0[r], Sl[j][0][r]);
        Sl[j][1][r] = fmaf(e, uh1[r], Sl[j][1][r]);
      }
    }
  }

#pragma unroll
  for (int j = 0; j < 4; ++j)
#pragma unroll
    for (int nt = 0; nt < 2; ++nt)
#pragma unroll
      for (int r = 0; r < 4; ++r)
        atomicAdd(S + (nt * 16 + ln) * UK + (u0 + j) * 16 + lq * 4 + r, Sl[j][nt][r]);
  if (l == 0) {
#pragma unroll
    for (int j = 0; j < 4; ++j) atomicAdd(Z + u0 + j, zloc[j]);
  }
  if (PASS == 1 && l < 16) {
#pragma unroll
    for (int j = 0; j < 4; ++j) b_io[(size_t)(c0 + l) * UU + u0 + j] = breg[j];
  }
}

// Final squash: s = S/Z ; mag_sq[b,k] = sum_u s^2 ; v = s*mag/(1+mag_sq).
__global__ void squash_k(const float* __restrict__ S, const float* __restrict__ Z,
                         float* __restrict__ vout)
{
  __shared__ float z_sh[UU];
  __shared__ float s2_sh[UK];
  __shared__ float mag_sh[16];

  const int b = blockIdx.x;
  const int t = threadIdx.x;

  if (t < UU) z_sh[t] = Z[t];
  float ssum = S[b * UK + t];
  __syncthreads();

  float s = ssum / z_sh[t >> 4];
  s2_sh[t] = s * s;
  __syncthreads();

  if (t < 16) {
    float m = 0.f;
    for (int uu = 0; uu < UU; ++uu) m += s2_sh[uu * 16 + t];
    mag_sh[t] = m;
  }
  __syncthreads();

  float msq = mag_sh[t & 15];
  vout[b * UK + t] = (msq / (1.0f + msq)) * s / sqrtf(msq);
}

extern "C" void kernel_launch(void* const* d_in, const int* in_sizes, int n_in,
                              void* d_out, int out_size, void* d_ws, size_t ws_size,
                              hipStream_t stream)
{
  const float* x = (const float*)d_in[0];   // (B, IN, C)
  const float* W = (const float*)d_in[1];   // (C, U, K, IN)
  float* out = (float*)d_out;               // (B, U, K, 1)

  char* ws = (char*)d_ws;
  const size_t SSLOT = (size_t)BB * UK * 4;                 // 64 KB
  float* S0  = (float*)ws;
  float* S1  = (float*)(ws + SSLOT);
  float* S2  = (float*)(ws + 2 * SSLOT);
  float* Z1  = (float*)(ws + 3 * SSLOT);
  float* Z2  = (float*)(ws + 3 * SSLOT + 128);
  float* bio = (float*)(ws + 3 * SSLOT + 256);              // C*U fp32 = 1 MB
  const size_t WBF_OFF = 3 * SSLOT + 256 + (size_t)CC * UU * 4;
  short* Wbf = (short*)(ws + WBF_OFF);                      // C*U*K*IN bf16 = 128 MB
  const size_t WBF_SZ = (size_t)CC * UK * INU * 2 + 1024;   // + OOB pad for masked lanes
  const bool use_wbf = ws_size >= WBF_OFF + WBF_SZ;

  (void)hipMemsetAsync(ws, 0, 3 * SSLOT + 256, stream);

  if (use_wbf) {
    gemm0<true><<<NCHUNK, 512, 0, stream>>>(x, W, S0, Wbf);
    route<1, true><<<NCHUNK, 512, 0, stream>>>(x, W, Wbf, bio, S0, nullptr, S1, Z1);
    route<2, true><<<NCHUNK, 512, 0, stream>>>(x, W, Wbf, bio, S1, Z1, S2, Z2);
  } else {
    gemm0<false><<<NCHUNK, 512, 0, stream>>>(x, W, S0, Wbf);
    route<1, false><<<NCHUNK, 512, 0, stream>>>(x, W, Wbf, bio, S0, nullptr, S1, Z1);
    route<2, false><<<NCHUNK, 512, 0, stream>>>(x, W, Wbf, bio, S1, Z1, S2, Z2);
  }
  squash_k<<<BB, 512, 0, stream>>>(S2, Z2, out);
}